// Round 5
// baseline (88.538 us; speedup 1.0000x reference)
//
#include <hip/hip_runtime.h>
#include <math.h>

#define T_LEN 200
#define CONST_MIN_F (-4294967295.0f)

typedef short bf8 __attribute__((ext_vector_type(8)));
typedef float f32x4 __attribute__((ext_vector_type(4)));

__device__ __forceinline__ float sigmoidf_(float x){ return 1.0f/(1.0f+__expf(-x)); }
__device__ __forceinline__ unsigned int pk_bf16(float lo, float hi){
  unsigned int r; asm("v_cvt_pk_bf16_f32 %0, %1, %2":"=v"(r):"v"(lo),"v"(hi)); return r;
}
union U4B8 { uint4 u; bf8 b; };
__device__ __forceinline__ bf8 pack8(float4 x, float4 y){
  U4B8 r;
  r.u.x = pk_bf16(x.x,x.y); r.u.y = pk_bf16(x.z,x.w);
  r.u.z = pk_bf16(y.x,y.y); r.u.w = pk_bf16(y.z,y.w);
  return r.b;
}
__device__ __forceinline__ bf8 pack8m(float4 x, float4 qx, float4 y, float4 qy){
  U4B8 r;
  r.u.x = pk_bf16(x.x*qx.x, x.y*qx.y); r.u.y = pk_bf16(x.z*qx.z, x.w*qx.w);
  r.u.z = pk_bf16(y.x*qy.x, y.y*qy.y); r.u.w = pk_bf16(y.z*qy.z, y.w*qy.w);
  return r.b;
}

// ws layout (float* wsf):
//   ushort fb[0..15360)     : A1 frags, 30 frags (ht 0..4 x ks 0..5), K=192:
//                             k 0..63 = k -> W1b-W1c; 64..127 = k*q -> W1d;
//                             128..191 = q -> W1a+W1c (folds q-term into MFMA)
//   ushort fb[15360..19968) : A2 frags (W2^T padded 48x96), 9 frags
//   wsf[9984..10032)        : b2 padded to 48 (f32)
//   wsf[10032..10080)       : Wf padded to 48 (f32)
// A-frag layout (16x16x32): row = lane&15, k = ks*32 + (lane>>4)*8 + e
__global__ void prep_kernel(const float* __restrict__ W1, const float* __restrict__ W2,
                            const float* __restrict__ b2, const float* __restrict__ Wf,
                            float* __restrict__ wsf){
  unsigned short* fb = (unsigned short*)wsf;
  int i = blockIdx.x*256 + threadIdx.x;
  if (i < 15360){
    int fi = i >> 9;                  // 0..29
    int lane = (i>>3)&63, e = i&7;
    int ht = fi/6, ks = fi%6;
    int h = ht*16 + (lane&15);
    int f = ks*32 + ((lane>>4)<<3) + e;
    float val;
    if (f < 64)        val = W1[(64+f)*80+h] - W1[(128+f)*80+h];
    else if (f < 128)  val = W1[(128+f)*80+h];
    else               val = W1[(f-128)*80+h] + W1[f*80+h];
    fb[i] = (unsigned short)(pk_bf16(val,val) & 0xffffu);
  }
  if (i < 4608){
    int fi = i >> 9;                  // 0..8
    int lane = (i>>3)&63, e = i&7;
    int gt = fi/3, ks = fi%3;
    int g = gt*16 + (lane&15);
    int h = ks*32 + ((lane>>4)<<3) + e;
    float val = (g<40 && h<80) ? W2[h*40+g] : 0.f;
    fb[15360+i] = (unsigned short)(pk_bf16(val,val) & 0xffffu);
  }
  if (i < 48){
    wsf[9984  + i] = (i<40) ? b2[i] : 0.f;
    wsf[10032 + i] = (i<40) ? Wf[i] : 0.f;
  }
}

__global__ __launch_bounds__(128, 4) void din_kernel(
    const float* __restrict__ q, const float* __restrict__ k, const float* __restrict__ v,
    const int* __restrict__ mask, const float* __restrict__ b1, const float* __restrict__ bf,
    const float* __restrict__ wsf, float* __restrict__ out)
{
  __shared__ float sm_s[256];
  __shared__ unsigned short tl[224];
  __shared__ int tot_s;
  __shared__ float red4[4];
  __shared__ __align__(16) unsigned int H_s[2*32*52];  // per-wave [32 item][52 u32]
  __shared__ float redpv[2*64];

  const int tid  = threadIdx.x;
  const int wid  = tid >> 6;
  const int lane = tid & 63;
  const int lg = lane>>4, lc = lane&15;
  const long b = blockIdx.x;
  const float* kb = k + b*(T_LEN*64);
  const float* vb = v + b*(T_LEN*64);
  const int*   mb = mask + b*T_LEN;
  const float* qb = q + b*64;
  const unsigned short* fbg = (const unsigned short*)wsf;
  const bf8* A1f = (const bf8*)fbg;
  const bf8* A2f = (const bf8*)(fbg + 15360);
  const float* b2p = wsf + 9984;
  const float* wfp = wsf + 10032;
  unsigned int* Hw = H_s + wid*(32*52);

  // per-lane q fragments (k-dims lg*8..+8 and 32+lg*8..+8)
  float4 qA0 = *(const float4*)(qb + lg*8);
  float4 qA1 = *(const float4*)(qb + lg*8 + 4);
  float4 qB0 = *(const float4*)(qb + 32 + lg*8);
  float4 qB1 = *(const float4*)(qb + 32 + lg*8 + 4);
  bf8 fq0 = pack8(qA0,qA1);
  bf8 fq1 = pack8(qB0,qB1);
  const float bf0 = bf[0];

  // zero own-wave H pad words (h 80..95): rows x words 40..47
  { uint4 z = {0,0,0,0}; *(uint4*)(Hw + (lane>>1)*52 + 40 + (lane&1)*4) = z; }

  // ---- compaction (wave 0 only) ----
  if (wid == 0){
    int tot = 0;
    unsigned long long ltm = (1ull<<lane) - 1ull;
    #pragma unroll
    for (int c=0;c<4;++c){
      int t = c*64 + lane;
      bool f = (t < T_LEN) && (mb[t] != 0);
      unsigned long long bal = __ballot(f);
      sm_s[t] = (t < T_LEN) ? (f ? 0.f : CONST_MIN_F) : -__builtin_inff();
      if (f) tl[tot + (int)__popcll(bal & ltm)] = (unsigned short)t;
      tot += (int)__popcll(bal);
    }
    if (lane == 0) tot_s = tot;
  }
  __syncthreads();
  const int tot = tot_s;

  // ---- passes of 32 items, waves interleaved, no cross-wave sync ----
  for (int base = wid*32; base < tot; base += 64){
    int t0 = tl[min(base+lc, tot-1)];
    int t1 = tl[min(base+16+lc, tot-1)];
    const float* kr0 = kb + t0*64 + lg*8;
    const float* kr1 = kb + t1*64 + lg*8;
    float4 a00 = *(const float4*)(kr0);
    float4 a01 = *(const float4*)(kr0+4);
    float4 b00 = *(const float4*)(kr0+32);
    float4 b01 = *(const float4*)(kr0+36);
    float4 a10 = *(const float4*)(kr1);
    float4 a11 = *(const float4*)(kr1+4);
    float4 b10 = *(const float4*)(kr1+32);
    float4 b11 = *(const float4*)(kr1+36);
    bf8 f00 = pack8(a00,a01),          f01 = pack8(b00,b01);
    bf8 f02 = pack8m(a00,qA0,a01,qA1), f03 = pack8m(b00,qB0,b01,qB1);
    bf8 f10 = pack8(a10,a11),          f11 = pack8(b10,b11);
    bf8 f12 = pack8m(a10,qA0,a11,qA1), f13 = pack8m(b10,qB0,b11,qB1);

    f32x4 acc0[5], acc1[5];
    #pragma unroll
    for (int ht=0; ht<5; ++ht){
      float4 bv = *(const float4*)(b1 + ht*16 + lg*4);
      acc0[ht][0]=bv.x; acc0[ht][1]=bv.y; acc0[ht][2]=bv.z; acc0[ht][3]=bv.w;
      acc1[ht][0]=bv.x; acc1[ht][1]=bv.y; acc1[ht][2]=bv.z; acc1[ht][3]=bv.w;
    }
    #pragma unroll
    for (int ht=0; ht<5; ++ht){
      bf8 afr;
      afr = A1f[(ht*6+0)*64+lane];
      acc0[ht] = __builtin_amdgcn_mfma_f32_16x16x32_bf16(afr, f00, acc0[ht],0,0,0);
      acc1[ht] = __builtin_amdgcn_mfma_f32_16x16x32_bf16(afr, f10, acc1[ht],0,0,0);
      afr = A1f[(ht*6+1)*64+lane];
      acc0[ht] = __builtin_amdgcn_mfma_f32_16x16x32_bf16(afr, f01, acc0[ht],0,0,0);
      acc1[ht] = __builtin_amdgcn_mfma_f32_16x16x32_bf16(afr, f11, acc1[ht],0,0,0);
      afr = A1f[(ht*6+2)*64+lane];
      acc0[ht] = __builtin_amdgcn_mfma_f32_16x16x32_bf16(afr, f02, acc0[ht],0,0,0);
      acc1[ht] = __builtin_amdgcn_mfma_f32_16x16x32_bf16(afr, f12, acc1[ht],0,0,0);
      afr = A1f[(ht*6+3)*64+lane];
      acc0[ht] = __builtin_amdgcn_mfma_f32_16x16x32_bf16(afr, f03, acc0[ht],0,0,0);
      acc1[ht] = __builtin_amdgcn_mfma_f32_16x16x32_bf16(afr, f13, acc1[ht],0,0,0);
      afr = A1f[(ht*6+4)*64+lane];
      acc0[ht] = __builtin_amdgcn_mfma_f32_16x16x32_bf16(afr, fq0, acc0[ht],0,0,0);
      acc1[ht] = __builtin_amdgcn_mfma_f32_16x16x32_bf16(afr, fq0, acc1[ht],0,0,0);
      afr = A1f[(ht*6+5)*64+lane];
      acc0[ht] = __builtin_amdgcn_mfma_f32_16x16x32_bf16(afr, fq1, acc0[ht],0,0,0);
      acc1[ht] = __builtin_amdgcn_mfma_f32_16x16x32_bf16(afr, fq1, acc1[ht],0,0,0);
    }

    // wave-local H bounce: ensure prior reads done, write sigmoid(h), wait, read frags
    asm volatile("s_waitcnt lgkmcnt(0)" ::: "memory");
    #pragma unroll
    for (int ht=0; ht<5; ++ht){
      #pragma unroll
      for (int rp=0; rp<2; ++rp){
        Hw[lc*52      + ht*8+lg*2+rp] = pk_bf16(sigmoidf_(acc0[ht][2*rp]), sigmoidf_(acc0[ht][2*rp+1]));
        Hw[(16+lc)*52 + ht*8+lg*2+rp] = pk_bf16(sigmoidf_(acc1[ht][2*rp]), sigmoidf_(acc1[ht][2*rp+1]));
      }
    }
    asm volatile("s_waitcnt lgkmcnt(0)" ::: "memory");
    __builtin_amdgcn_sched_barrier(0);

    bf8 c0[3], c1[3];
    #pragma unroll
    for (int ks=0; ks<3; ++ks){
      c0[ks] = *(const bf8*)(Hw + lc*52      + 16*ks + 4*lg);
      c1[ks] = *(const bf8*)(Hw + (16+lc)*52 + 16*ks + 4*lg);
    }
    f32x4 g0[3], g1[3];
    #pragma unroll
    for (int gt=0; gt<3; ++gt){
      float4 bv = *(const float4*)(b2p + gt*16 + lg*4);
      g0[gt][0]=bv.x; g0[gt][1]=bv.y; g0[gt][2]=bv.z; g0[gt][3]=bv.w;
      g1[gt][0]=bv.x; g1[gt][1]=bv.y; g1[gt][2]=bv.z; g1[gt][3]=bv.w;
    }
    #pragma unroll
    for (int gt=0; gt<3; ++gt){
      #pragma unroll
      for (int ks=0; ks<3; ++ks){
        bf8 afr = A2f[(gt*3+ks)*64+lane];
        g0[gt] = __builtin_amdgcn_mfma_f32_16x16x32_bf16(afr, c0[ks], g0[gt],0,0,0);
        g1[gt] = __builtin_amdgcn_mfma_f32_16x16x32_bf16(afr, c1[ks], g1[gt],0,0,0);
      }
    }
    float p0=0.f, p1=0.f;
    #pragma unroll
    for (int gt=0; gt<3; ++gt){
      float4 wv = *(const float4*)(wfp + gt*16 + lg*4);
      float wvv[4] = {wv.x, wv.y, wv.z, wv.w};
      #pragma unroll
      for (int r=0;r<4;++r){
        p0 = fmaf(wvv[r], sigmoidf_(g0[gt][r]), p0);
        p1 = fmaf(wvv[r], sigmoidf_(g1[gt][r]), p1);
      }
    }
    p0 += __shfl_xor(p0,16); p0 += __shfl_xor(p0,32);
    p1 += __shfl_xor(p1,16); p1 += __shfl_xor(p1,32);
    if (lg==0){
      if (base+lc    < tot) sm_s[tl[base+lc]]    = p0 + bf0;
      if (base+16+lc < tot) sm_s[tl[base+16+lc]] = p1 + bf0;
    }
  }
  __syncthreads();

  // ---- softmax over 256 slots (128 threads, cross-wave combine) ----
  float l0 = sm_s[tid], l1 = sm_s[tid+128];
  float m = fmaxf(l0, l1);
  #pragma unroll
  for (int off=1; off<64; off<<=1) m = fmaxf(m, __shfl_xor(m,off));
  if (lane == 0) red4[wid] = m;
  __syncthreads();
  float M = fmaxf(red4[0], red4[1]);
  float e0 = __expf(l0 - M), e1 = __expf(l1 - M);
  float s = e0 + e1;
  #pragma unroll
  for (int off=1; off<64; off<<=1) s += __shfl_xor(s,off);
  if (lane == 0) red4[2+wid] = s;
  __syncthreads();
  float S = red4[2] + red4[3];
  float inv = 1.0f / S;
  sm_s[tid]     = e0 * inv;
  sm_s[tid+128] = e1 * inv;
  __syncthreads();

  // ---- PV: waves split items ----
  float acc = 0.f;
  if (tot > 0){
    int i = wid;
    for (; i+4 <= tot; i += 4){
      int ta = tl[i], tb_ = tl[i+2];
      acc = fmaf(sm_s[ta],  vb[ta*64+lane],  acc);
      acc = fmaf(sm_s[tb_], vb[tb_*64+lane], acc);
    }
    for (; i < tot; i += 2){ int t = tl[i]; acc = fmaf(sm_s[t], vb[t*64+lane], acc); }
  } else {
    for (int t = wid; t < T_LEN; t += 2) acc = fmaf(sm_s[t], vb[t*64+lane], acc);
  }
  redpv[wid*64 + lane] = acc;
  __syncthreads();
  if (tid < 64) out[b*64+tid] = redpv[tid] + redpv[64+tid];
}

extern "C" void kernel_launch(void* const* d_in, const int* in_sizes, int n_in,
                              void* d_out, int out_size, void* d_ws, size_t ws_size,
                              hipStream_t stream) {
  const float* q    = (const float*)d_in[0];
  const float* k    = (const float*)d_in[1];
  const float* v    = (const float*)d_in[2];
  const int*   mask = (const int*)d_in[3];
  const float* W1   = (const float*)d_in[4];
  const float* b1   = (const float*)d_in[5];
  const float* W2   = (const float*)d_in[6];
  const float* b2   = (const float*)d_in[7];
  const float* Wf   = (const float*)d_in[8];
  const float* bf   = (const float*)d_in[9];
  float* out = (float*)d_out;
  float* wsf = (float*)d_ws;   // needs 10080 floats = 40320 B

  hipLaunchKernelGGL(prep_kernel, dim3(60), dim3(256), 0, stream, W1, W2, b2, Wf, wsf);
  hipLaunchKernelGGL(din_kernel, dim3(2048), dim3(128), 0, stream,
                     q, k, v, mask, b1, bf, wsf, out);
}

// Round 6
// 73.580 us; speedup vs baseline: 1.2033x; 1.2033x over previous
//
#include <hip/hip_runtime.h>
#include <math.h>

#define T_LEN 200
#define CONST_MIN_F (-4294967295.0f)

typedef short bf8 __attribute__((ext_vector_type(8)));
typedef float f32x4 __attribute__((ext_vector_type(4)));

__device__ __forceinline__ float sigmoidf_(float x){ return 1.0f/(1.0f+__expf(-x)); }
__device__ __forceinline__ unsigned int pk_bf16(float lo, float hi){
  unsigned int r; asm("v_cvt_pk_bf16_f32 %0, %1, %2":"=v"(r):"v"(lo),"v"(hi)); return r;
}
union U4B8 { uint4 u; bf8 b; };
__device__ __forceinline__ bf8 pack8(float4 x, float4 y){
  U4B8 r;
  r.u.x = pk_bf16(x.x,x.y); r.u.y = pk_bf16(x.z,x.w);
  r.u.z = pk_bf16(y.x,y.y); r.u.w = pk_bf16(y.z,y.w);
  return r.b;
}
__device__ __forceinline__ bf8 pack8m(float4 x, float4 qx, float4 y, float4 qy){
  U4B8 r;
  r.u.x = pk_bf16(x.x*qx.x, x.y*qx.y); r.u.y = pk_bf16(x.z*qx.z, x.w*qx.w);
  r.u.z = pk_bf16(y.x*qy.x, y.y*qy.y); r.u.w = pk_bf16(y.z*qy.z, y.w*qy.w);
  return r.b;
}

// ws layout (float* wsf):
//   ushort fb[0..15360)     : A1 frags, 30 frags (ht 0..4 x ks 0..5), K=192:
//                             k 0..63 = k -> W1b-W1c; 64..127 = k*q -> W1d;
//                             128..191 = q -> W1a+W1c (folds q-term into MFMA)
//   ushort fb[15360..19968) : A2 frags (W2^T padded 48x96), 9 frags
//   wsf[9984..10032)        : b2 padded to 48 (f32)
//   wsf[10032..10080)       : Wf padded to 48 (f32)
// A-frag layout (16x16x32): row = lane&15, k = ks*32 + (lane>>4)*8 + e
__global__ void prep_kernel(const float* __restrict__ W1, const float* __restrict__ W2,
                            const float* __restrict__ b2, const float* __restrict__ Wf,
                            float* __restrict__ wsf){
  unsigned short* fb = (unsigned short*)wsf;
  int i = blockIdx.x*256 + threadIdx.x;
  if (i < 15360){
    int fi = i >> 9;                  // 0..29
    int lane = (i>>3)&63, e = i&7;
    int ht = fi/6, ks = fi%6;
    int h = ht*16 + (lane&15);
    int f = ks*32 + ((lane>>4)<<3) + e;
    float val;
    if (f < 64)        val = W1[(64+f)*80+h] - W1[(128+f)*80+h];
    else if (f < 128)  val = W1[(128+f)*80+h];
    else               val = W1[(f-128)*80+h] + W1[f*80+h];
    fb[i] = (unsigned short)(pk_bf16(val,val) & 0xffffu);
  }
  if (i < 4608){
    int fi = i >> 9;                  // 0..8
    int lane = (i>>3)&63, e = i&7;
    int gt = fi/3, ks = fi%3;
    int g = gt*16 + (lane&15);
    int h = ks*32 + ((lane>>4)<<3) + e;
    float val = (g<40 && h<80) ? W2[h*40+g] : 0.f;
    fb[15360+i] = (unsigned short)(pk_bf16(val,val) & 0xffffu);
  }
  if (i < 48){
    wsf[9984  + i] = (i<40) ? b2[i] : 0.f;
    wsf[10032 + i] = (i<40) ? Wf[i] : 0.f;
  }
}

__global__ __launch_bounds__(128, 2) void din_kernel(
    const float* __restrict__ q, const float* __restrict__ k, const float* __restrict__ v,
    const int* __restrict__ mask, const float* __restrict__ b1, const float* __restrict__ bf,
    const float* __restrict__ wsf, float* __restrict__ out)
{
  __shared__ float sm_s[256];
  __shared__ unsigned short tl[224];
  __shared__ int tot_s;
  __shared__ float red4[4];
  __shared__ __align__(16) unsigned int H_s[2*32*52];  // per-wave [32 item][52 u32]
  __shared__ float redpv[2*64];

  const int tid  = threadIdx.x;
  const int wid  = tid >> 6;
  const int lane = tid & 63;
  const int lg = lane>>4, lc = lane&15;
  const long b = blockIdx.x;
  const float* kb = k + b*(T_LEN*64);
  const float* vb = v + b*(T_LEN*64);
  const int*   mb = mask + b*T_LEN;
  const float* qb = q + b*64;
  const unsigned short* fbg = (const unsigned short*)wsf;
  const bf8* A1f = (const bf8*)fbg;
  const bf8* A2f = (const bf8*)(fbg + 15360);
  const float* b2p = wsf + 9984;
  const float* wfp = wsf + 10032;
  unsigned int* Hw = H_s + wid*(32*52);

  // per-lane q fragments (k-dims lg*8..+8 and 32+lg*8..+8)
  float4 qA0 = *(const float4*)(qb + lg*8);
  float4 qA1 = *(const float4*)(qb + lg*8 + 4);
  float4 qB0 = *(const float4*)(qb + 32 + lg*8);
  float4 qB1 = *(const float4*)(qb + 32 + lg*8 + 4);
  bf8 fq0 = pack8(qA0,qA1);
  bf8 fq1 = pack8(qB0,qB1);
  const float bf0 = bf[0];

  // zero own-wave H pad words (h 80..95): rows x words 40..47
  { uint4 z = {0,0,0,0}; *(uint4*)(Hw + (lane>>1)*52 + 40 + (lane&1)*4) = z; }

  // ---- compaction (wave 0 only) ----
  if (wid == 0){
    int tot = 0;
    unsigned long long ltm = (1ull<<lane) - 1ull;
    #pragma unroll
    for (int c=0;c<4;++c){
      int t = c*64 + lane;
      bool f = (t < T_LEN) && (mb[t] != 0);
      unsigned long long bal = __ballot(f);
      sm_s[t] = (t < T_LEN) ? (f ? 0.f : CONST_MIN_F) : -__builtin_inff();
      if (f) tl[tot + (int)__popcll(bal & ltm)] = (unsigned short)t;
      tot += (int)__popcll(bal);
    }
    if (lane == 0) tot_s = tot;
  }
  __syncthreads();
  const int tot = tot_s;

  // ---- passes of 32 items, waves interleaved, no cross-wave sync ----
  for (int base = wid*32; base < tot; base += 64){
    int t0 = tl[min(base+lc, tot-1)];
    int t1 = tl[min(base+16+lc, tot-1)];
    const float* kr0 = kb + t0*64 + lg*8;
    const float* kr1 = kb + t1*64 + lg*8;
    float4 a00 = *(const float4*)(kr0);
    float4 a01 = *(const float4*)(kr0+4);
    float4 b00 = *(const float4*)(kr0+32);
    float4 b01 = *(const float4*)(kr0+36);
    float4 a10 = *(const float4*)(kr1);
    float4 a11 = *(const float4*)(kr1+4);
    float4 b10 = *(const float4*)(kr1+32);
    float4 b11 = *(const float4*)(kr1+36);
    bf8 f00 = pack8(a00,a01),          f01 = pack8(b00,b01);
    bf8 f02 = pack8m(a00,qA0,a01,qA1), f03 = pack8m(b00,qB0,b01,qB1);
    bf8 f10 = pack8(a10,a11),          f11 = pack8(b10,b11);
    bf8 f12 = pack8m(a10,qA0,a11,qA1), f13 = pack8m(b10,qB0,b11,qB1);

    f32x4 acc0[5], acc1[5];
    #pragma unroll
    for (int ht=0; ht<5; ++ht){
      float4 bv = *(const float4*)(b1 + ht*16 + lg*4);
      acc0[ht][0]=bv.x; acc0[ht][1]=bv.y; acc0[ht][2]=bv.z; acc0[ht][3]=bv.w;
      acc1[ht][0]=bv.x; acc1[ht][1]=bv.y; acc1[ht][2]=bv.z; acc1[ht][3]=bv.w;
    }
    #pragma unroll
    for (int ht=0; ht<5; ++ht){
      bf8 afr;
      afr = A1f[(ht*6+0)*64+lane];
      acc0[ht] = __builtin_amdgcn_mfma_f32_16x16x32_bf16(afr, f00, acc0[ht],0,0,0);
      acc1[ht] = __builtin_amdgcn_mfma_f32_16x16x32_bf16(afr, f10, acc1[ht],0,0,0);
      afr = A1f[(ht*6+1)*64+lane];
      acc0[ht] = __builtin_amdgcn_mfma_f32_16x16x32_bf16(afr, f01, acc0[ht],0,0,0);
      acc1[ht] = __builtin_amdgcn_mfma_f32_16x16x32_bf16(afr, f11, acc1[ht],0,0,0);
      afr = A1f[(ht*6+2)*64+lane];
      acc0[ht] = __builtin_amdgcn_mfma_f32_16x16x32_bf16(afr, f02, acc0[ht],0,0,0);
      acc1[ht] = __builtin_amdgcn_mfma_f32_16x16x32_bf16(afr, f12, acc1[ht],0,0,0);
      afr = A1f[(ht*6+3)*64+lane];
      acc0[ht] = __builtin_amdgcn_mfma_f32_16x16x32_bf16(afr, f03, acc0[ht],0,0,0);
      acc1[ht] = __builtin_amdgcn_mfma_f32_16x16x32_bf16(afr, f13, acc1[ht],0,0,0);
      afr = A1f[(ht*6+4)*64+lane];
      acc0[ht] = __builtin_amdgcn_mfma_f32_16x16x32_bf16(afr, fq0, acc0[ht],0,0,0);
      acc1[ht] = __builtin_amdgcn_mfma_f32_16x16x32_bf16(afr, fq0, acc1[ht],0,0,0);
      afr = A1f[(ht*6+5)*64+lane];
      acc0[ht] = __builtin_amdgcn_mfma_f32_16x16x32_bf16(afr, fq1, acc0[ht],0,0,0);
      acc1[ht] = __builtin_amdgcn_mfma_f32_16x16x32_bf16(afr, fq1, acc1[ht],0,0,0);
    }

    // wave-local H bounce: ensure prior reads done, write sigmoid(h), wait, read frags
    asm volatile("s_waitcnt lgkmcnt(0)" ::: "memory");
    #pragma unroll
    for (int ht=0; ht<5; ++ht){
      #pragma unroll
      for (int rp=0; rp<2; ++rp){
        Hw[lc*52      + ht*8+lg*2+rp] = pk_bf16(sigmoidf_(acc0[ht][2*rp]), sigmoidf_(acc0[ht][2*rp+1]));
        Hw[(16+lc)*52 + ht*8+lg*2+rp] = pk_bf16(sigmoidf_(acc1[ht][2*rp]), sigmoidf_(acc1[ht][2*rp+1]));
      }
    }
    asm volatile("s_waitcnt lgkmcnt(0)" ::: "memory");
    __builtin_amdgcn_sched_barrier(0);

    bf8 c0[3], c1[3];
    #pragma unroll
    for (int ks=0; ks<3; ++ks){
      c0[ks] = *(const bf8*)(Hw + lc*52      + 16*ks + 4*lg);
      c1[ks] = *(const bf8*)(Hw + (16+lc)*52 + 16*ks + 4*lg);
    }
    f32x4 g0[3], g1[3];
    #pragma unroll
    for (int gt=0; gt<3; ++gt){
      float4 bv = *(const float4*)(b2p + gt*16 + lg*4);
      g0[gt][0]=bv.x; g0[gt][1]=bv.y; g0[gt][2]=bv.z; g0[gt][3]=bv.w;
      g1[gt][0]=bv.x; g1[gt][1]=bv.y; g1[gt][2]=bv.z; g1[gt][3]=bv.w;
    }
    #pragma unroll
    for (int gt=0; gt<3; ++gt){
      #pragma unroll
      for (int ks=0; ks<3; ++ks){
        bf8 afr = A2f[(gt*3+ks)*64+lane];
        g0[gt] = __builtin_amdgcn_mfma_f32_16x16x32_bf16(afr, c0[ks], g0[gt],0,0,0);
        g1[gt] = __builtin_amdgcn_mfma_f32_16x16x32_bf16(afr, c1[ks], g1[gt],0,0,0);
      }
    }
    float p0=0.f, p1=0.f;
    #pragma unroll
    for (int gt=0; gt<3; ++gt){
      float4 wv = *(const float4*)(wfp + gt*16 + lg*4);
      float wvv[4] = {wv.x, wv.y, wv.z, wv.w};
      #pragma unroll
      for (int r=0;r<4;++r){
        p0 = fmaf(wvv[r], sigmoidf_(g0[gt][r]), p0);
        p1 = fmaf(wvv[r], sigmoidf_(g1[gt][r]), p1);
      }
    }
    p0 += __shfl_xor(p0,16); p0 += __shfl_xor(p0,32);
    p1 += __shfl_xor(p1,16); p1 += __shfl_xor(p1,32);
    if (lg==0){
      if (base+lc    < tot) sm_s[tl[base+lc]]    = p0 + bf0;
      if (base+16+lc < tot) sm_s[tl[base+16+lc]] = p1 + bf0;
    }
  }
  __syncthreads();

  // ---- softmax over 256 slots (128 threads, cross-wave combine) ----
  float l0 = sm_s[tid], l1 = sm_s[tid+128];
  float m = fmaxf(l0, l1);
  #pragma unroll
  for (int off=1; off<64; off<<=1) m = fmaxf(m, __shfl_xor(m,off));
  if (lane == 0) red4[wid] = m;
  __syncthreads();
  float M = fmaxf(red4[0], red4[1]);
  float e0 = __expf(l0 - M), e1 = __expf(l1 - M);
  float s = e0 + e1;
  #pragma unroll
  for (int off=1; off<64; off<<=1) s += __shfl_xor(s,off);
  if (lane == 0) red4[2+wid] = s;
  __syncthreads();
  float S = red4[2] + red4[3];
  float inv = 1.0f / S;
  sm_s[tid]     = e0 * inv;
  sm_s[tid+128] = e1 * inv;
  __syncthreads();

  // ---- PV: waves split items ----
  float acc = 0.f;
  if (tot > 0){
    int i = wid;
    for (; i+4 <= tot; i += 4){
      int ta = tl[i], tb_ = tl[i+2];
      acc = fmaf(sm_s[ta],  vb[ta*64+lane],  acc);
      acc = fmaf(sm_s[tb_], vb[tb_*64+lane], acc);
    }
    for (; i < tot; i += 2){ int t = tl[i]; acc = fmaf(sm_s[t], vb[t*64+lane], acc); }
  } else {
    for (int t = wid; t < T_LEN; t += 2) acc = fmaf(sm_s[t], vb[t*64+lane], acc);
  }
  redpv[wid*64 + lane] = acc;
  __syncthreads();
  if (tid < 64) out[b*64+tid] = redpv[tid] + redpv[64+tid];
}

extern "C" void kernel_launch(void* const* d_in, const int* in_sizes, int n_in,
                              void* d_out, int out_size, void* d_ws, size_t ws_size,
                              hipStream_t stream) {
  const float* q    = (const float*)d_in[0];
  const float* k    = (const float*)d_in[1];
  const float* v    = (const float*)d_in[2];
  const int*   mask = (const int*)d_in[3];
  const float* W1   = (const float*)d_in[4];
  const float* b1   = (const float*)d_in[5];
  const float* W2   = (const float*)d_in[6];
  const float* b2   = (const float*)d_in[7];
  const float* Wf   = (const float*)d_in[8];
  const float* bf   = (const float*)d_in[9];
  float* out = (float*)d_out;
  float* wsf = (float*)d_ws;   // needs 10080 floats = 40320 B

  hipLaunchKernelGGL(prep_kernel, dim3(60), dim3(256), 0, stream, W1, W2, b2, Wf, wsf);
  hipLaunchKernelGGL(din_kernel, dim3(2048), dim3(128), 0, stream,
                     q, k, v, mask, b1, bf, wsf, out);
}

// Round 7
// 61.260 us; speedup vs baseline: 1.4453x; 1.2011x over previous
//
#include <hip/hip_runtime.h>
#include <math.h>

#define T_LEN 200
#define CONST_MIN_F (-4294967295.0f)
#define LG_STRIDE 256
#define LG_FLOATS (2048 * 256)

typedef short bf8 __attribute__((ext_vector_type(8)));
typedef float f32x4 __attribute__((ext_vector_type(4)));

__device__ __forceinline__ float sigmoidf_(float x){ return 1.0f/(1.0f+__expf(-x)); }
__device__ __forceinline__ unsigned int pk_bf16(float lo, float hi){
  unsigned int r; asm("v_cvt_pk_bf16_f32 %0, %1, %2":"=v"(r):"v"(lo),"v"(hi)); return r;
}
union U4B8 { uint4 u; bf8 b; };
__device__ __forceinline__ bf8 pack8(float4 x, float4 y){
  U4B8 r;
  r.u.x = pk_bf16(x.x,x.y); r.u.y = pk_bf16(x.z,x.w);
  r.u.z = pk_bf16(y.x,y.y); r.u.w = pk_bf16(y.z,y.w);
  return r.b;
}
__device__ __forceinline__ bf8 pack8m(float4 x, float4 qx, float4 y, float4 qy){
  U4B8 r;
  r.u.x = pk_bf16(x.x*qx.x, x.y*qx.y); r.u.y = pk_bf16(x.z*qx.z, x.w*qx.w);
  r.u.z = pk_bf16(y.x*qy.x, y.y*qy.y); r.u.w = pk_bf16(y.z*qy.z, y.w*qy.w);
  return r.b;
}

// ws layout (float* wsf):
//   wsf[0 .. 524288)                  : logits [2048][256] f32
//   ushort fb = (ushort*)(wsf+524288) : fb[0..15360) A1 frags (30), K=192:
//                                       k 0..63 = k -> W1b-W1c; 64..127 = k*q -> W1d;
//                                       128..191 = q -> W1a+W1c (q-term folded into MFMA)
//                                       fb[15360..19968) A2 frags (W2^T padded 48x96)
//   wsf[524288+9984  .. +48)          : b2 padded to 48
//   wsf[524288+10032 .. +48)          : Wf padded to 48
// A-frag layout (16x16x32): row = lane&15, k = ks*32 + (lane>>4)*8 + e
__global__ void prep_kernel(const float* __restrict__ W1, const float* __restrict__ W2,
                            const float* __restrict__ b2, const float* __restrict__ Wf,
                            float* __restrict__ wsf){
  unsigned short* fb = (unsigned short*)(wsf + LG_FLOATS);
  int i = blockIdx.x*256 + threadIdx.x;
  if (i < 15360){
    int fi = i >> 9;                  // 0..29
    int lane = (i>>3)&63, e = i&7;
    int ht = fi/6, ks = fi%6;
    int h = ht*16 + (lane&15);
    int f = ks*32 + ((lane>>4)<<3) + e;
    float val;
    if (f < 64)        val = W1[(64+f)*80+h] - W1[(128+f)*80+h];
    else if (f < 128)  val = W1[(128+f)*80+h];
    else               val = W1[(f-128)*80+h] + W1[f*80+h];
    fb[i] = (unsigned short)(pk_bf16(val,val) & 0xffffu);
  }
  if (i < 4608){
    int fi = i >> 9;                  // 0..8
    int lane = (i>>3)&63, e = i&7;
    int gt = fi/3, ks = fi%3;
    int g = gt*16 + (lane&15);
    int h = ks*32 + ((lane>>4)<<3) + e;
    float val = (g<40 && h<80) ? W2[h*40+g] : 0.f;
    fb[15360+i] = (unsigned short)(pk_bf16(val,val) & 0xffffu);
  }
  if (i < 48){
    wsf[LG_FLOATS + 9984  + i] = (i<40) ? b2[i] : 0.f;
    wsf[LG_FLOATS + 10032 + i] = (i<40) ? Wf[i] : 0.f;
  }
}

// One wave per (b, segment-of-100-t). 4096 blocks -> 16 blocks/CU.
__global__ __launch_bounds__(64) void logits_kernel(
    const float* __restrict__ q, const float* __restrict__ k,
    const int* __restrict__ mask, const float* __restrict__ b1,
    const float* __restrict__ bf, const float* __restrict__ wsf,
    float* __restrict__ lgp)
{
  __shared__ unsigned short tl[112];
  __shared__ __align__(16) unsigned int Hw[32*52];   // [32 item][52 u32], words 40..47 zero

  const int lane = threadIdx.x;
  const int lg = lane>>4, lc = lane&15;
  const int bid = blockIdx.x;
  const long b = bid >> 1;
  const int tbase = (bid & 1) * 100;

  const float* kb = k + b*(T_LEN*64);
  const int*   mb = mask + b*T_LEN;
  const float* qb = q + b*64;
  const unsigned short* fbg = (const unsigned short*)(wsf + LG_FLOATS);
  const bf8* A1f = (const bf8*)fbg;
  const bf8* A2f = (const bf8*)(fbg + 15360);
  const float* b2p = wsf + LG_FLOATS + 9984;
  const float* wfp = wsf + LG_FLOATS + 10032;
  float* lgb = lgp + b*LG_STRIDE;

  // per-lane q fragments (k-dims lg*8..+8 and 32+lg*8..+8)
  float4 qA0 = *(const float4*)(qb + lg*8);
  float4 qA1 = *(const float4*)(qb + lg*8 + 4);
  float4 qB0 = *(const float4*)(qb + 32 + lg*8);
  float4 qB1 = *(const float4*)(qb + 32 + lg*8 + 4);
  bf8 fq0 = pack8(qA0,qA1);
  bf8 fq1 = pack8(qB0,qB1);
  const float bf0 = bf[0];

  // zero H pad words (h 80..95)
  { uint4 z = {0,0,0,0}; *(uint4*)(Hw + (lane>>1)*52 + 40 + (lane&1)*4) = z; }

  // ---- compaction over this segment's 100 t's ----
  unsigned long long ltm = (1ull<<lane) - 1ull;
  bool f0 = (mb[tbase + lane] != 0);
  unsigned long long bal0 = __ballot(f0);
  bool f1 = (lane < 36) && (mb[tbase + 64 + lane] != 0);
  unsigned long long bal1 = __ballot(f1);
  int c0 = (int)__popcll(bal0);
  int tot = c0 + (int)__popcll(bal1);
  if (f0) tl[(int)__popcll(bal0 & ltm)] = (unsigned short)(tbase + lane);
  if (f1) tl[c0 + (int)__popcll(bal1 & ltm)] = (unsigned short)(tbase + 64 + lane);
  if (!f0) lgb[tbase + lane] = CONST_MIN_F;
  if (lane < 36 && !f1) lgb[tbase + 64 + lane] = CONST_MIN_F;
  __syncthreads();

  // ---- passes of 32 items (2 MFMA tiles) ----
  for (int base = 0; base < tot; base += 32){
    int t0 = tl[min(base+lc, tot-1)];
    int t1 = tl[min(base+16+lc, tot-1)];
    const float* kr0 = kb + t0*64 + lg*8;
    const float* kr1 = kb + t1*64 + lg*8;
    float4 a00 = *(const float4*)(kr0);
    float4 a01 = *(const float4*)(kr0+4);
    float4 b00 = *(const float4*)(kr0+32);
    float4 b01 = *(const float4*)(kr0+36);
    float4 a10 = *(const float4*)(kr1);
    float4 a11 = *(const float4*)(kr1+4);
    float4 b10 = *(const float4*)(kr1+32);
    float4 b11 = *(const float4*)(kr1+36);
    bf8 f00 = pack8(a00,a01),          f01 = pack8(b00,b01);
    bf8 f02 = pack8m(a00,qA0,a01,qA1), f03 = pack8m(b00,qB0,b01,qB1);
    bf8 f10 = pack8(a10,a11),          f11 = pack8(b10,b11);
    bf8 f12 = pack8m(a10,qA0,a11,qA1), f13 = pack8m(b10,qB0,b11,qB1);

    f32x4 acc0[5], acc1[5];
    #pragma unroll
    for (int ht=0; ht<5; ++ht){
      float4 bv = *(const float4*)(b1 + ht*16 + lg*4);
      acc0[ht][0]=bv.x; acc0[ht][1]=bv.y; acc0[ht][2]=bv.z; acc0[ht][3]=bv.w;
      acc1[ht][0]=bv.x; acc1[ht][1]=bv.y; acc1[ht][2]=bv.z; acc1[ht][3]=bv.w;
    }
    #pragma unroll
    for (int ht=0; ht<5; ++ht){
      bf8 afr;
      afr = A1f[(ht*6+0)*64+lane];
      acc0[ht] = __builtin_amdgcn_mfma_f32_16x16x32_bf16(afr, f00, acc0[ht],0,0,0);
      acc1[ht] = __builtin_amdgcn_mfma_f32_16x16x32_bf16(afr, f10, acc1[ht],0,0,0);
      afr = A1f[(ht*6+1)*64+lane];
      acc0[ht] = __builtin_amdgcn_mfma_f32_16x16x32_bf16(afr, f01, acc0[ht],0,0,0);
      acc1[ht] = __builtin_amdgcn_mfma_f32_16x16x32_bf16(afr, f11, acc1[ht],0,0,0);
      afr = A1f[(ht*6+2)*64+lane];
      acc0[ht] = __builtin_amdgcn_mfma_f32_16x16x32_bf16(afr, f02, acc0[ht],0,0,0);
      acc1[ht] = __builtin_amdgcn_mfma_f32_16x16x32_bf16(afr, f12, acc1[ht],0,0,0);
      afr = A1f[(ht*6+3)*64+lane];
      acc0[ht] = __builtin_amdgcn_mfma_f32_16x16x32_bf16(afr, f03, acc0[ht],0,0,0);
      acc1[ht] = __builtin_amdgcn_mfma_f32_16x16x32_bf16(afr, f13, acc1[ht],0,0,0);
      afr = A1f[(ht*6+4)*64+lane];
      acc0[ht] = __builtin_amdgcn_mfma_f32_16x16x32_bf16(afr, fq0, acc0[ht],0,0,0);
      acc1[ht] = __builtin_amdgcn_mfma_f32_16x16x32_bf16(afr, fq0, acc1[ht],0,0,0);
      afr = A1f[(ht*6+5)*64+lane];
      acc0[ht] = __builtin_amdgcn_mfma_f32_16x16x32_bf16(afr, fq1, acc0[ht],0,0,0);
      acc1[ht] = __builtin_amdgcn_mfma_f32_16x16x32_bf16(afr, fq1, acc1[ht],0,0,0);
    }

    // sigmoid -> H (bf16 pairs), 1-wave LDS bounce
    #pragma unroll
    for (int ht=0; ht<5; ++ht){
      #pragma unroll
      for (int rp=0; rp<2; ++rp){
        Hw[lc*52      + ht*8+lg*2+rp] = pk_bf16(sigmoidf_(acc0[ht][2*rp]), sigmoidf_(acc0[ht][2*rp+1]));
        Hw[(16+lc)*52 + ht*8+lg*2+rp] = pk_bf16(sigmoidf_(acc1[ht][2*rp]), sigmoidf_(acc1[ht][2*rp+1]));
      }
    }
    __syncthreads();

    bf8 c0[3], c1[3];
    #pragma unroll
    for (int ks=0; ks<3; ++ks){
      c0[ks] = *(const bf8*)(Hw + lc*52      + 16*ks + 4*lg);
      c1[ks] = *(const bf8*)(Hw + (16+lc)*52 + 16*ks + 4*lg);
    }
    f32x4 g0[3], g1[3];
    #pragma unroll
    for (int gt=0; gt<3; ++gt){
      float4 bv = *(const float4*)(b2p + gt*16 + lg*4);
      g0[gt][0]=bv.x; g0[gt][1]=bv.y; g0[gt][2]=bv.z; g0[gt][3]=bv.w;
      g1[gt][0]=bv.x; g1[gt][1]=bv.y; g1[gt][2]=bv.z; g1[gt][3]=bv.w;
    }
    #pragma unroll
    for (int gt=0; gt<3; ++gt){
      #pragma unroll
      for (int ks=0; ks<3; ++ks){
        bf8 afr = A2f[(gt*3+ks)*64+lane];
        g0[gt] = __builtin_amdgcn_mfma_f32_16x16x32_bf16(afr, c0[ks], g0[gt],0,0,0);
        g1[gt] = __builtin_amdgcn_mfma_f32_16x16x32_bf16(afr, c1[ks], g1[gt],0,0,0);
      }
    }
    float p0=0.f, p1=0.f;
    #pragma unroll
    for (int gt=0; gt<3; ++gt){
      float4 wv = *(const float4*)(wfp + gt*16 + lg*4);
      float wvv[4] = {wv.x, wv.y, wv.z, wv.w};
      #pragma unroll
      for (int r=0;r<4;++r){
        p0 = fmaf(wvv[r], sigmoidf_(g0[gt][r]), p0);
        p1 = fmaf(wvv[r], sigmoidf_(g1[gt][r]), p1);
      }
    }
    p0 += __shfl_xor(p0,16); p0 += __shfl_xor(p0,32);
    p1 += __shfl_xor(p1,16); p1 += __shfl_xor(p1,32);
    if (lg==0){
      if (base+lc    < tot) lgb[tl[base+lc]]    = p0 + bf0;
      if (base+16+lc < tot) lgb[tl[base+16+lc]] = p1 + bf0;
    }
    __syncthreads();
  }
}

// One wave per b: softmax over logits row + mask-compacted PV.
__global__ __launch_bounds__(64) void smpv_kernel(
    const float* __restrict__ v, const int* __restrict__ mask,
    const float* __restrict__ lgp, float* __restrict__ out)
{
  __shared__ float sm_s[256];
  __shared__ unsigned short tl[224];
  const int lane = threadIdx.x;
  const long b = blockIdx.x;
  const float* vb = v + b*(T_LEN*64);
  const int*   mb = mask + b*T_LEN;
  const float* lb = lgp + b*LG_STRIDE;

  float l0 = lb[lane], l1 = lb[64+lane], l2 = lb[128+lane];
  float l3 = (lane<8) ? lb[192+lane] : -__builtin_inff();
  float m = fmaxf(fmaxf(l0,l1), fmaxf(l2,l3));
  #pragma unroll
  for (int off=1; off<64; off<<=1) m = fmaxf(m, __shfl_xor(m,off));
  float e0=__expf(l0-m), e1=__expf(l1-m), e2=__expf(l2-m);
  float e3=(lane<8)? __expf(l3-m) : 0.f;
  float s = e0+e1+e2+e3;
  #pragma unroll
  for (int off=1; off<64; off<<=1) s += __shfl_xor(s,off);
  float inv = 1.0f/s;
  sm_s[lane]      = e0*inv;
  sm_s[64+lane]   = e1*inv;
  sm_s[128+lane]  = e2*inv;
  if (lane<8) sm_s[192+lane] = e3*inv;

  int tot = 0;
  unsigned long long ltm = (1ull<<lane)-1ull;
  #pragma unroll
  for (int c=0;c<4;++c){
    int t = c*64 + lane;
    bool f = (t < T_LEN) && (mb[t] != 0);
    unsigned long long bal = __ballot(f);
    if (f) tl[tot + (int)__popcll(bal & ltm)] = (unsigned short)t;
    tot += (int)__popcll(bal);
  }
  __syncthreads();

  float acc = 0.f;
  if (tot > 0){
    int i = 0;
    for (; i+4 <= tot; i += 4){
      int ta=tl[i], tb_=tl[i+1], tc_=tl[i+2], td_=tl[i+3];
      acc = fmaf(sm_s[ta],  vb[ta*64+lane],  acc);
      acc = fmaf(sm_s[tb_], vb[tb_*64+lane], acc);
      acc = fmaf(sm_s[tc_], vb[tc_*64+lane], acc);
      acc = fmaf(sm_s[td_], vb[td_*64+lane], acc);
    }
    for (; i < tot; ++i){ int t = tl[i]; acc = fmaf(sm_s[t], vb[t*64+lane], acc); }
  } else {
    for (int t = 0; t < T_LEN; ++t) acc = fmaf(sm_s[t], vb[t*64+lane], acc);
  }
  out[b*64+lane] = acc;
}

extern "C" void kernel_launch(void* const* d_in, const int* in_sizes, int n_in,
                              void* d_out, int out_size, void* d_ws, size_t ws_size,
                              hipStream_t stream) {
  const float* q    = (const float*)d_in[0];
  const float* k    = (const float*)d_in[1];
  const float* v    = (const float*)d_in[2];
  const int*   mask = (const int*)d_in[3];
  const float* W1   = (const float*)d_in[4];
  const float* b1   = (const float*)d_in[5];
  const float* W2   = (const float*)d_in[6];
  const float* b2   = (const float*)d_in[7];
  const float* Wf   = (const float*)d_in[8];
  const float* bf   = (const float*)d_in[9];
  float* out = (float*)d_out;
  float* wsf = (float*)d_ws;   // needs (524288 + 10080)*4 ≈ 2.14 MB

  hipLaunchKernelGGL(prep_kernel, dim3(60), dim3(256), 0, stream, W1, W2, b2, Wf, wsf);
  hipLaunchKernelGGL(logits_kernel, dim3(4096), dim3(64), 0, stream,
                     q, k, mask, b1, bf, wsf, wsf);
  hipLaunchKernelGGL(smpv_kernel, dim3(2048), dim3(64), 0, stream,
                     v, mask, wsf, out);
}